// Round 8
// baseline (36.091 us; speedup 1.0000x reference)
//
#include <hip/hip_runtime.h>
#include <hip/hip_bf16.h>
#include <math.h>

#define NCONF  256
#define NATOMS 128
#define NATOT  (NCONF * NATOMS)
#define PER_ATOM 1216        // 9*64 + 4*64 + 6*64
#define ABLK   16            // atoms per block
#define NBLK   (NATOT / ABLK)   // 2048 blocks = 8 per CU

// constants: K = 8*log2(e); SQK = sqrt(K); HS = 2^(-7/8) / 2
#define SQK      3.3972871196167196f
#define SK_STEP  0.32355115424921137f   // SQK * 6/63
#define SK_BASE -10.191861358850159f    // -3 * SQK
#define HS       0.27262693316631437f

typedef float f32x4 __attribute__((ext_vector_type(4)));

__device__ __forceinline__ int species_to_sidx(int z) {
    switch (z) {
        case 1:  return 0;
        case 6:  return 1;
        case 7:  return 2;
        case 8:  return 3;
        case 9:  return 4;
        case 16: return 5;
        default: return 6;   // 17
    }
}

__global__ __launch_bounds__(256) void aev_fused_kernel(
    const float* __restrict__ coeff,   // (NATOT, 21) f32
    const float* __restrict__ nlib,    // (4, 7, 9) f32
    const int*   __restrict__ sp32,    // species, int32 OR int64 (detected)
    float* __restrict__ out)           // (NATOT, 1216) f32
{
    __shared__ float c_sh[ABLK][21];       // staged coefficients
    __shared__ float pars[ABLK][25];       // X[0..12], A[13..18], B[19..24]
    __shared__ float Mn_sh[ABLK][4][3];    // normalized p-vectors
    __shared__ int   sidx_sh[ABLK];
    __shared__ float ct_sh[64], st_sh[64]; // cos/sin of shfT grid

    const int tid = threadIdx.x;
    const int a0  = blockIdx.x * ABLK;

    // ---- phase 0: table + coalesced coeff staging + species ----
    if (tid < 64) {
        float t = (float)tid * (float)(M_PI / 63.0);
        ct_sh[tid] = __cosf(t);
        st_sh[tid] = __sinf(t);
    }
    #pragma unroll
    for (int i = tid; i < ABLK * 21; i += 256) {     // 336 floats, coalesced
        c_sh[i / 21][i % 21] = coeff[(size_t)a0 * 21 + i];
    }
    if (tid < ABLK) {
        // species dtype runtime detection: int64 => sp32[1] is high word of
        // species[0] == 0; int32 => sp32[1] in {1,6,7,8,9,16,17} != 0.
        const int is64 = (sp32[1] == 0);
        const int atom = a0 + tid;
        const int z = is64 ? sp32[(size_t)atom * 2] : sp32[atom];
        sidx_sh[tid] = species_to_sidx(z);
    }
    __syncthreads();

    // ---- phase 1: s-channels (144 thr) + p-norms (64 thr) ----
    if (tid < 144) {
        int a = tid / 9, k = tid - a * 9;
        int sidx = sidx_sh[a];
        float mu = nlib[0 * 63 + sidx * 9 + k];
        float sg = nlib[1 * 63 + sidx * 9 + k];
        pars[a][k] = SQK * (c_sh[a][k] - mu) / sg;
    } else if (tid < 208) {
        int t = tid - 144;
        int a = t >> 2, i = t & 3;
        float x = c_sh[a][9 + i * 3 + 0];
        float y = c_sh[a][9 + i * 3 + 1];
        float w = c_sh[a][9 + i * 3 + 2];
        float nn  = x * x + y * y + w * w;
        float nrm = sqrtf(nn);
        bool zero = (fabsf(x) < 1e-12f) && (fabsf(y) < 1e-12f) &&
                    (fabsf(w) < 1e-12f);
        int sidx = sidx_sh[a];
        float mu = nlib[2 * 63 + sidx * 9 + i];
        float sg = nlib[3 * 63 + sidx * 9 + i];
        pars[a][9 + i] = SQK * (nrm - mu) / sg;
        float inv = zero ? 0.0f : (1.0f / nrm);
        Mn_sh[a][i][0] = x * inv;
        Mn_sh[a][i][1] = y * inv;
        Mn_sh[a][i][2] = w * inv;
    }
    __syncthreads();

    // ---- phase 2: pair angles (96 thr) ----
    if (tid < 96) {
        int a = tid / 6, p = tid - a * 6;
        const int iu[6] = {0, 0, 0, 1, 1, 2};
        const int ju[6] = {1, 2, 3, 2, 3, 3};
        int i = iu[p], j = ju[p];
        float d = Mn_sh[a][i][0] * Mn_sh[a][j][0] +
                  Mn_sh[a][i][1] * Mn_sh[a][j][1] +
                  Mn_sh[a][i][2] * Mn_sh[a][j][2];
        d = fminf(fmaxf(d, -0.9999f), 0.9999f);
        float sa = sqrtf(fmaxf(1.0f - d * d, 0.0f));
        pars[a][13 + p] = HS * d;    // A
        pars[a][19 + p] = HS * sa;   // B
    }
    __syncthreads();

    float* po_blk = out + (size_t)a0 * PER_ATOM;

    // ---- phase 3a: radial, 16 atoms x 208 quads = 3328 = 13 x 256 (uniform) ----
    #pragma unroll
    for (int it = 0; it < 13; ++it) {
        int idx = it * 256 + tid;
        int a   = idx / 208;             // magic-mul
        int rq  = idx - a * 208;         // quad within atom, 0..207
        float X = pars[a][rq >> 4];
        float b = fmaf((float)((rq & 15) << 2), SK_STEP, SK_BASE);
        float d0 = X - b;
        float d1 = d0 - SK_STEP;
        float d2 = d1 - SK_STEP;
        float d3 = d2 - SK_STEP;
        f32x4 v;
        v.x = exp2f(-(d0 * d0));
        v.y = exp2f(-(d1 * d1));
        v.z = exp2f(-(d2 * d2));
        v.w = exp2f(-(d3 * d3));
        __builtin_nontemporal_store(v,
            reinterpret_cast<f32x4*>(po_blk + a * PER_ATOM + rq * 4));
    }

    // ---- phase 3b: angular, 16 atoms x 96 quads = 1536 = 6 x 256 (uniform) ----
    #pragma unroll
    for (int it = 0; it < 6; ++it) {
        int idx = it * 256 + tid;
        int a   = idx / 96;              // magic-mul
        int aq  = idx - a * 96;          // 0..95
        int p   = aq >> 4;
        int j0  = (aq & 15) << 2;
        float Ap = pars[a][13 + p];
        float Bp = pars[a][19 + p];
        float4 ct = *reinterpret_cast<const float4*>(&ct_sh[j0]);
        float4 st = *reinterpret_cast<const float4*>(&st_sh[j0]);
        float u0 = fmaf(Ap, ct.x, fmaf(Bp, st.x, HS));
        float u1 = fmaf(Ap, ct.y, fmaf(Bp, st.y, HS));
        float u2 = fmaf(Ap, ct.z, fmaf(Bp, st.z, HS));
        float u3 = fmaf(Ap, ct.w, fmaf(Bp, st.w, HS));
        f32x4 v;
        u0 *= u0; u0 *= u0; v.x = u0 * u0;   // u^8
        u1 *= u1; u1 *= u1; v.y = u1 * u1;
        u2 *= u2; u2 *= u2; v.z = u2 * u2;
        u3 *= u3; u3 *= u3; v.w = u3 * u3;
        __builtin_nontemporal_store(v,
            reinterpret_cast<f32x4*>(po_blk + a * PER_ATOM + 832 + aq * 4));
    }
}

extern "C" void kernel_launch(void* const* d_in, const int* in_sizes, int n_in,
                              void* d_out, int out_size, void* d_ws, size_t ws_size,
                              hipStream_t stream) {
    const float* coeff   = (const float*)d_in[0];
    const float* nlib    = (const float*)d_in[1];
    const int*   sp32    = (const int*)d_in[2];
    float* out           = (float*)d_out;

    aev_fused_kernel<<<dim3(NBLK), dim3(256), 0, stream>>>(
        coeff, nlib, sp32, out);
}

// Round 9
// 32.038 us; speedup vs baseline: 1.1265x; 1.1265x over previous
//
#include <hip/hip_runtime.h>
#include <hip/hip_bf16.h>
#include <math.h>

#define NCONF  256
#define NATOMS 128
#define NATOT  (NCONF * NATOMS)
#define PER_ATOM 1216        // 9*64 + 4*64 + 6*64
#define ABLK   16            // atoms per group
#define GRPS   2             // groups per block
#define NBLK   (NATOT / (ABLK * GRPS))   // 1024 blocks = 4 per CU exact

// constants: K = 8*log2(e); SQK = sqrt(K); HS = 2^(-7/8) / 2
#define SQK      3.3972871196167196f
#define SK_STEP  0.32355115424921137f   // SQK * 6/63
#define SK_BASE -10.191861358850159f    // -3 * SQK
#define HS       0.27262693316631437f

__device__ __forceinline__ int species_to_sidx(int z) {
    switch (z) {
        case 1:  return 0;
        case 6:  return 1;
        case 7:  return 2;
        case 8:  return 3;
        case 9:  return 4;
        case 16: return 5;
        default: return 6;   // 17
    }
}

__global__ __launch_bounds__(256) void aev_persist_kernel(
    const float* __restrict__ coeff,   // (NATOT, 21) f32
    const float* __restrict__ nlib,    // (4, 7, 9) f32
    const int*   __restrict__ sp32,    // species, int32 OR int64 (detected)
    float* __restrict__ out)           // (NATOT, 1216) f32
{
    __shared__ float c_sh[ABLK][21];       // staged coefficients (current group)
    __shared__ float pars[ABLK][25];       // X[0..12], A[13..18], B[19..24]
    __shared__ float Mn_sh[ABLK][4][3];    // normalized p-vectors
    __shared__ int   sidx_sh[ABLK];
    __shared__ float ct_sh[64], st_sh[64]; // cos/sin of shfT grid

    const int tid = threadIdx.x;
    const int a0  = blockIdx.x * (ABLK * GRPS);   // 32 atoms, contiguous 156KB out

    // species dtype runtime detection: int64 => sp32[1] is high word of
    // species[0] == 0; int32 => sp32[1] in {1,6,7,8,9,16,17} != 0.
    const int is64 = (sp32[1] == 0);

    // ---- phase 0: table + group-0 coeff staging + species ----
    if (tid < 64) {
        float t = (float)tid * (float)(M_PI / 63.0);
        ct_sh[tid] = __cosf(t);
        st_sh[tid] = __sinf(t);
    }
    #pragma unroll
    for (int i = tid; i < ABLK * 21; i += 256) {     // 336 floats, coalesced
        c_sh[i / 21][i % 21] = coeff[(size_t)a0 * 21 + i];
    }
    if (tid < ABLK) {
        const int atom = a0 + tid;
        const int z = is64 ? sp32[(size_t)atom * 2] : sp32[atom];
        sidx_sh[tid] = species_to_sidx(z);
    }
    __syncthreads();

    #pragma unroll
    for (int g = 0; g < GRPS; ++g) {
        // ---- phase 1: s-channels (144 thr) + p-norms (64 thr) ----
        if (tid < 144) {
            int a = tid / 9, k = tid - a * 9;
            int sidx = sidx_sh[a];
            float mu = nlib[0 * 63 + sidx * 9 + k];
            float sg = nlib[1 * 63 + sidx * 9 + k];
            pars[a][k] = SQK * (c_sh[a][k] - mu) / sg;
        } else if (tid < 208) {
            int t = tid - 144;
            int a = t >> 2, i = t & 3;
            float x = c_sh[a][9 + i * 3 + 0];
            float y = c_sh[a][9 + i * 3 + 1];
            float w = c_sh[a][9 + i * 3 + 2];
            float nn  = x * x + y * y + w * w;
            float nrm = sqrtf(nn);
            bool zero = (fabsf(x) < 1e-12f) && (fabsf(y) < 1e-12f) &&
                        (fabsf(w) < 1e-12f);
            int sidx = sidx_sh[a];
            float mu = nlib[2 * 63 + sidx * 9 + i];
            float sg = nlib[3 * 63 + sidx * 9 + i];
            pars[a][9 + i] = SQK * (nrm - mu) / sg;
            float inv = zero ? 0.0f : (1.0f / nrm);
            Mn_sh[a][i][0] = x * inv;
            Mn_sh[a][i][1] = y * inv;
            Mn_sh[a][i][2] = w * inv;
        }
        __syncthreads();

        // ---- phase 2: pair angles (96 thr) ----
        if (tid < 96) {
            int a = tid / 6, p = tid - a * 6;
            const int iu[6] = {0, 0, 0, 1, 1, 2};
            const int ju[6] = {1, 2, 3, 2, 3, 3};
            int i = iu[p], j = ju[p];
            float d = Mn_sh[a][i][0] * Mn_sh[a][j][0] +
                      Mn_sh[a][i][1] * Mn_sh[a][j][1] +
                      Mn_sh[a][i][2] * Mn_sh[a][j][2];
            d = fminf(fmaxf(d, -0.9999f), 0.9999f);
            float sa = sqrtf(fmaxf(1.0f - d * d, 0.0f));
            pars[a][13 + p] = HS * d;    // A
            pars[a][19 + p] = HS * sa;   // B
        }
        __syncthreads();

        // ---- prefetch next group's inputs into registers (overlaps stores) ----
        float pf0 = 0.0f, pf1 = 0.0f;
        int   sidx_n = 0;
        if (g + 1 < GRPS) {
            const float* cn = coeff + ((size_t)a0 + (g + 1) * ABLK) * 21;
            pf0 = cn[tid];                       // tid < 256 < 336: always valid
            if (tid < ABLK * 21 - 256) pf1 = cn[256 + tid];
            if (tid < ABLK) {
                const int atom = a0 + (g + 1) * ABLK + tid;
                const int z = is64 ? sp32[(size_t)atom * 2] : sp32[atom];
                sidx_n = species_to_sidx(z);
            }
        }

        float* po_blk = out + (size_t)(a0 + g * ABLK) * PER_ATOM;

        // ---- phase 3a: radial, 16 atoms x 208 quads = 13 x 256 (uniform) ----
        #pragma unroll
        for (int it = 0; it < 13; ++it) {
            int idx = it * 256 + tid;
            int a   = idx / 208;             // magic-mul
            int rq  = idx - a * 208;         // quad within atom, 0..207
            float X = pars[a][rq >> 4];
            float b = fmaf((float)((rq & 15) << 2), SK_STEP, SK_BASE);
            float d0 = X - b;
            float d1 = d0 - SK_STEP;
            float d2 = d1 - SK_STEP;
            float d3 = d2 - SK_STEP;
            float4 v;
            v.x = exp2f(-(d0 * d0));
            v.y = exp2f(-(d1 * d1));
            v.z = exp2f(-(d2 * d2));
            v.w = exp2f(-(d3 * d3));
            *reinterpret_cast<float4*>(po_blk + a * PER_ATOM + rq * 4) = v;
        }

        // ---- phase 3b: angular, 16 atoms x 96 quads = 6 x 256 (uniform) ----
        #pragma unroll
        for (int it = 0; it < 6; ++it) {
            int idx = it * 256 + tid;
            int a   = idx / 96;              // magic-mul
            int aq  = idx - a * 96;          // 0..95
            int p   = aq >> 4;
            int j0  = (aq & 15) << 2;
            float Ap = pars[a][13 + p];
            float Bp = pars[a][19 + p];
            float4 ct = *reinterpret_cast<const float4*>(&ct_sh[j0]);
            float4 st = *reinterpret_cast<const float4*>(&st_sh[j0]);
            float u0 = fmaf(Ap, ct.x, fmaf(Bp, st.x, HS));
            float u1 = fmaf(Ap, ct.y, fmaf(Bp, st.y, HS));
            float u2 = fmaf(Ap, ct.z, fmaf(Bp, st.z, HS));
            float u3 = fmaf(Ap, ct.w, fmaf(Bp, st.w, HS));
            float4 v;
            u0 *= u0; u0 *= u0; v.x = u0 * u0;   // u^8
            u1 *= u1; u1 *= u1; v.y = u1 * u1;
            u2 *= u2; u2 *= u2; v.z = u2 * u2;
            u3 *= u3; u3 *= u3; v.w = u3 * u3;
            *reinterpret_cast<float4*>(po_blk + a * PER_ATOM + 832 + aq * 4) = v;
        }

        // ---- hand prefetched inputs to shared for the next group ----
        if (g + 1 < GRPS) {
            __syncthreads();   // pars/c_sh/sidx_sh dead for group g now
            c_sh[tid / 21][tid % 21] = pf0;
            if (tid < ABLK * 21 - 256) {
                int i2 = 256 + tid;
                c_sh[i2 / 21][i2 % 21] = pf1;
            }
            if (tid < ABLK) sidx_sh[tid] = sidx_n;
            __syncthreads();
        }
    }
}

extern "C" void kernel_launch(void* const* d_in, const int* in_sizes, int n_in,
                              void* d_out, int out_size, void* d_ws, size_t ws_size,
                              hipStream_t stream) {
    const float* coeff   = (const float*)d_in[0];
    const float* nlib    = (const float*)d_in[1];
    const int*   sp32    = (const int*)d_in[2];
    float* out           = (float*)d_out;

    aev_persist_kernel<<<dim3(NBLK), dim3(256), 0, stream>>>(
        coeff, nlib, sp32, out);
}

// Round 10
// 31.612 us; speedup vs baseline: 1.1417x; 1.0135x over previous
//
#include <hip/hip_runtime.h>
#include <hip/hip_bf16.h>
#include <math.h>

#define NCONF  256
#define NATOMS 128
#define NATOT  (NCONF * NATOMS)
#define PER_ATOM 1216        // 9*64 + 4*64 + 6*64
#define ABLK   16            // atoms per block
#define NBLK   (NATOT / ABLK)   // 2048 blocks = 8 per CU

// constants: K = 8*log2(e); SQK = sqrt(K); HS = 2^(-7/8) / 2
#define SQK      3.3972871196167196f
#define SK_STEP  0.32355115424921137f   // SQK * 6/63
#define SK_BASE -10.191861358850159f    // -3 * SQK
#define HS       0.27262693316631437f

__device__ __forceinline__ int species_to_sidx(int z) {
    switch (z) {
        case 1:  return 0;
        case 6:  return 1;
        case 7:  return 2;
        case 8:  return 3;
        case 9:  return 4;
        case 16: return 5;
        default: return 6;   // 17
    }
}

__global__ __launch_bounds__(256) void aev_fused_kernel(
    const float* __restrict__ coeff,   // (NATOT, 21) f32
    const float* __restrict__ nlib,    // (4, 7, 9) f32
    const int*   __restrict__ sp32,    // species, int32 OR int64 (detected)
    float* __restrict__ out)           // (NATOT, 1216) f32
{
    __shared__ float pars[ABLK][25];       // X[0..12], A[13..18], B[19..24]
    __shared__ float ct_sh[64], st_sh[64]; // cos/sin of shfT grid

    const int tid = threadIdx.x;
    const int a0  = blockIdx.x * ABLK;

    // species dtype runtime detection: int64 => sp32[1] is high word of
    // species[0] == 0; int32 => sp32[1] in {1,6,7,8,9,16,17} != 0.
    const int is64 = (sp32[1] == 0);

    // ---- single setup phase: all tasks independent, ONE barrier ----
    if (tid < 64) {
        float t = (float)tid * (float)(M_PI / 63.0);
        ct_sh[tid] = __cosf(t);
        st_sh[tid] = __sinf(t);
    }

    if (tid < 144) {
        // s-channels: 16 atoms x 9 = 144 tasks
        int a = tid / 9, k = tid - a * 9;
        int atom = a0 + a;
        int z = is64 ? sp32[(size_t)atom * 2] : sp32[atom];
        int sidx = species_to_sidx(z);
        float cv = coeff[(size_t)atom * 21 + k];
        float mu = nlib[0 * 63 + sidx * 9 + k];
        float sg = nlib[1 * 63 + sidx * 9 + k];
        pars[a][k] = SQK * (cv - mu) / sg;
    } else if (tid < 208) {
        // p-norm channels: 16 atoms x 4 = 64 tasks
        int t = tid - 144;
        int a = t >> 2, i = t & 3;
        int atom = a0 + a;
        int z = is64 ? sp32[(size_t)atom * 2] : sp32[atom];
        int sidx = species_to_sidx(z);
        const float* cp = coeff + (size_t)atom * 21 + 9 + i * 3;
        float x = cp[0], y = cp[1], w = cp[2];
        float nrm = sqrtf(x * x + y * y + w * w);
        float mu = nlib[2 * 63 + sidx * 9 + i];
        float sg = nlib[3 * 63 + sidx * 9 + i];
        pars[a][9 + i] = SQK * (nrm - mu) / sg;
    } else {
        // pair angles: 16 atoms x 6 = 96 tasks on 48 threads (2 each),
        // independent of the p-norm task (norms recomputed locally)
        int t = tid - 208;
        const int iu[6] = {0, 0, 0, 1, 1, 2};
        const int ju[6] = {1, 2, 3, 2, 3, 3};
        #pragma unroll
        for (int u = 0; u < 2; ++u) {
            int pp = t * 2 + u;          // 0..95
            int a  = pp / 6, p = pp - a * 6;
            int i = iu[p], j = ju[p];
            const float* cp = coeff + (size_t)(a0 + a) * 21 + 9;
            float xi = cp[i * 3], yi = cp[i * 3 + 1], wi = cp[i * 3 + 2];
            float xj = cp[j * 3], yj = cp[j * 3 + 1], wj = cp[j * 3 + 2];
            float ni2 = xi * xi + yi * yi + wi * wi;
            float nj2 = xj * xj + yj * yj + wj * wj;
            bool zi = (fabsf(xi) < 1e-12f) && (fabsf(yi) < 1e-12f) &&
                      (fabsf(wi) < 1e-12f);
            bool zj = (fabsf(xj) < 1e-12f) && (fabsf(yj) < 1e-12f) &&
                      (fabsf(wj) < 1e-12f);
            float d = (zi || zj) ? 0.0f
                                 : (xi * xj + yi * yj + wi * wj) * rsqrtf(ni2 * nj2);
            d = fminf(fmaxf(d, -0.9999f), 0.9999f);
            float sa = sqrtf(fmaxf(1.0f - d * d, 0.0f));
            pars[a][13 + p] = HS * d;    // A
            pars[a][19 + p] = HS * sa;   // B
        }
    }
    __syncthreads();

    float* po_blk = out + (size_t)a0 * PER_ATOM;

    // ---- radial: 16 atoms x 208 quads = 3328 = 13 x 256 (uniform) ----
    #pragma unroll
    for (int it = 0; it < 13; ++it) {
        int idx = it * 256 + tid;
        int a   = idx / 208;             // magic-mul
        int rq  = idx - a * 208;         // quad within atom, 0..207
        float X = pars[a][rq >> 4];
        float b = fmaf((float)((rq & 15) << 2), SK_STEP, SK_BASE);
        float d0 = X - b;
        float d1 = d0 - SK_STEP;
        float d2 = d1 - SK_STEP;
        float d3 = d2 - SK_STEP;
        float4 v;
        v.x = exp2f(-(d0 * d0));
        v.y = exp2f(-(d1 * d1));
        v.z = exp2f(-(d2 * d2));
        v.w = exp2f(-(d3 * d3));
        *reinterpret_cast<float4*>(po_blk + a * PER_ATOM + rq * 4) = v;
    }

    // ---- angular: 16 atoms x 96 quads = 1536 = 6 x 256 (uniform) ----
    #pragma unroll
    for (int it = 0; it < 6; ++it) {
        int idx = it * 256 + tid;
        int a   = idx / 96;              // magic-mul
        int aq  = idx - a * 96;          // 0..95
        int p   = aq >> 4;
        int j0  = (aq & 15) << 2;
        float Ap = pars[a][13 + p];
        float Bp = pars[a][19 + p];
        float4 ct = *reinterpret_cast<const float4*>(&ct_sh[j0]);
        float4 st = *reinterpret_cast<const float4*>(&st_sh[j0]);
        float u0 = fmaf(Ap, ct.x, fmaf(Bp, st.x, HS));
        float u1 = fmaf(Ap, ct.y, fmaf(Bp, st.y, HS));
        float u2 = fmaf(Ap, ct.z, fmaf(Bp, st.z, HS));
        float u3 = fmaf(Ap, ct.w, fmaf(Bp, st.w, HS));
        float4 v;
        u0 *= u0; u0 *= u0; v.x = u0 * u0;   // u^8
        u1 *= u1; u1 *= u1; v.y = u1 * u1;
        u2 *= u2; u2 *= u2; v.z = u2 * u2;
        u3 *= u3; u3 *= u3; v.w = u3 * u3;
        *reinterpret_cast<float4*>(po_blk + a * PER_ATOM + 832 + aq * 4) = v;
    }
}

extern "C" void kernel_launch(void* const* d_in, const int* in_sizes, int n_in,
                              void* d_out, int out_size, void* d_ws, size_t ws_size,
                              hipStream_t stream) {
    const float* coeff   = (const float*)d_in[0];
    const float* nlib    = (const float*)d_in[1];
    const int*   sp32    = (const int*)d_in[2];
    float* out           = (float*)d_out;

    aev_fused_kernel<<<dim3(NBLK), dim3(256), 0, stream>>>(
        coeff, nlib, sp32, out);
}